// Round 4
// baseline (3136.115 us; speedup 1.0000x reference)
//
#include <hip/hip_runtime.h>

typedef _Float16 f16;
typedef _Float16 half8 __attribute__((ext_vector_type(8)));
typedef float f32x4 __attribute__((ext_vector_type(4)));
typedef unsigned int u32x4 __attribute__((ext_vector_type(4)));
typedef unsigned int u32x2 __attribute__((ext_vector_type(2)));

#define HIDDEN 1024
#define NSER 512
#define BATCH 256
#define TSTEPS 512

__device__ __forceinline__ float tanh_fast(float x) {
  x = fminf(15.0f, fmaxf(-15.0f, x));
  float e = __expf(2.0f * x);
  return (e - 1.0f) / (e + 1.0f);
}

// ---------------- prep kernels (unchanged from R3) ----------------

__global__ __launch_bounds__(256) void convert_whl_kernel(const float* __restrict__ Wh,
                                                          f16* __restrict__ WhLh) {
  int idx = blockIdx.x * 256 + threadIdx.x;  // 1024*1024
  int j = idx >> 10, k = idx & 1023;
  WhLh[idx] = (f16)Wh[((size_t)j << 11) + k];
}

__global__ __launch_bounds__(256) void convert_wl_kernel(const float* __restrict__ Wl,
                                                         f16* __restrict__ Wlh) {
  int idx = blockIdx.x * 256 + threadIdx.x;  // 512*1024
  Wlh[idx] = (f16)Wl[idx];
}

__global__ __launch_bounds__(256) void transpose_wi_kernel(const float* __restrict__ Wi,
                                                           f16* __restrict__ WiT) {
  __shared__ float tile[32][33];
  int tx = threadIdx.x & 31, ty = threadIdx.x >> 5;
  int c0 = blockIdx.x * 32;  // n (512)
  int r0 = blockIdx.y * 32;  // k (1024)
#pragma unroll
  for (int i = 0; i < 32; i += 8)
    tile[ty + i][tx] = Wi[(size_t)(r0 + ty + i) * NSER + c0 + tx];
  __syncthreads();
#pragma unroll
  for (int i = 0; i < 32; i += 8)
    WiT[(size_t)(c0 + ty + i) * HIDDEN + r0 + tx] = (f16)tile[tx][ty + i];
}

__global__ __launch_bounds__(256) void transpose_x_kernel(const float* __restrict__ x,
                                                          f16* __restrict__ xT) {
  __shared__ float tile[32][33];
  int b = blockIdx.z;
  int t0 = blockIdx.x * 32, n0 = blockIdx.y * 32;
  int tx = threadIdx.x & 31, ty = threadIdx.x >> 5;
#pragma unroll
  for (int i = 0; i < 32; i += 8)
    tile[ty + i][tx] = x[((size_t)b * NSER + n0 + ty + i) * TSTEPS + t0 + tx];
  __syncthreads();
#pragma unroll
  for (int i = 0; i < 32; i += 8)
    xT[((size_t)(t0 + ty + i) * BATCH + b) * NSER + n0 + tx] = (f16)tile[tx][ty + i];
}

__global__ __launch_bounds__(256) void beff_kernel(const float* __restrict__ Wh,
                                                   const float* __restrict__ bi,
                                                   const float* __restrict__ bh,
                                                   float* __restrict__ beff) {
  __shared__ float red[256];
  int j = blockIdx.x;
  float s = 0.f;
  for (int k = threadIdx.x; k < HIDDEN; k += 256)
    s += Wh[(size_t)j * 2048 + k] * bi[k];
  red[threadIdx.x] = s;
  __syncthreads();
  for (int off = 128; off > 0; off >>= 1) {
    if (threadIdx.x < (unsigned)off) red[threadIdx.x] += red[threadIdx.x + off];
    __syncthreads();
  }
  if (threadIdx.x == 0) beff[j] = bh[j] + red[0];
}

// ---------------- generic f16 MFMA GEMM: C[M,N] = A[M,K] * B[N,K]^T (+bias[n]) ----------------
template <bool OUT_F16, bool HAS_BIAS>
__global__ __launch_bounds__(256) void gemm_f16_kernel(const f16* __restrict__ A,
                                                       const f16* __restrict__ B,
                                                       const float* __restrict__ bias,
                                                       void* __restrict__ Cp,
                                                       int M, int N, int K) {
  (void)M;
  __shared__ f16 As[128 * 64];
  __shared__ f16 Bs[128 * 64];
  const int tid = threadIdx.x;
  const int l = tid & 63, w = tid >> 6;
  const int wr = w >> 1, wc = w & 1;
  const int lr = l & 15, lg = l >> 4;
  const size_t m0 = (size_t)blockIdx.y * 128, n0 = (size_t)blockIdx.x * 128;
  f32x4 acc[4][4] = {};
  for (int k0 = 0; k0 < K; k0 += 64) {
    half8 ar[4], br[4];
#pragma unroll
    for (int c = 0; c < 4; ++c) {
      int Gq = c * 256 + tid;            // granule 0..1023 (16B each)
      int row = Gq >> 3, colg = Gq & 7;  // row 0..127, col granule 0..7
      ar[c] = *(const half8*)&A[(m0 + row) * K + k0 + colg * 8];
      br[c] = *(const half8*)&B[(n0 + row) * K + k0 + colg * 8];
    }
    __syncthreads();  // previous iter's LDS reads done
#pragma unroll
    for (int c = 0; c < 4; ++c) {
      int Gq = c * 256 + tid;
      *(half8*)&As[Gq * 8] = ar[c];
      *(half8*)&Bs[Gq * 8] = br[c];
    }
    __syncthreads();
#pragma unroll
    for (int ks = 0; ks < 2; ++ks) {
      half8 a[4], b[4];
#pragma unroll
      for (int i = 0; i < 4; ++i)
        a[i] = *(const half8*)&As[(wr * 64 + i * 16 + lr) * 64 + ks * 32 + lg * 8];
#pragma unroll
      for (int i = 0; i < 4; ++i)
        b[i] = *(const half8*)&Bs[(wc * 64 + i * 16 + lr) * 64 + ks * 32 + lg * 8];
#pragma unroll
      for (int mi = 0; mi < 4; ++mi)
#pragma unroll
        for (int ni = 0; ni < 4; ++ni)
          acc[mi][ni] = __builtin_amdgcn_mfma_f32_16x16x32_f16(a[mi], b[ni], acc[mi][ni], 0, 0, 0);
    }
  }
#pragma unroll
  for (int mi = 0; mi < 4; ++mi) {
#pragma unroll
    for (int ni = 0; ni < 4; ++ni) {
      size_t n = n0 + wc * 64 + ni * 16 + lr;
      float bv = 0.f;
      if constexpr (HAS_BIAS) bv = bias[n];
#pragma unroll
      for (int r = 0; r < 4; ++r) {
        size_t m = m0 + wr * 64 + mi * 16 + lg * 4 + r;
        float v = acc[mi][ni][r] + bv;
        if constexpr (OUT_F16)
          ((f16*)Cp)[m * (size_t)N + n] = (f16)v;
        else
          ((float*)Cp)[m * (size_t)N + n] = v;
      }
    }
  }
}

// ---------------- persistent recurrent kernel: tagged-dword mailbox ----------------
// 128 blocks x 512 threads = 16 b-groups (16 rows) x 8 j-blocks (128 cols).
// Mailbox word = (step_tag << 16) | f16(h). Producer stores are fire-and-forget
// (per-dword atomicity = self-describing); the consumer's poll IS the data load.
// All loop VMEM is inline asm -> hand-counted vmcnt: issue 8 h-loads, then 4
// Z(t+1) prefetch loads, s_waitcnt vmcnt(4) waits h only (Z flies a full step).
// Raw s_barrier (+lgkmcnt) instead of __syncthreads: no per-step vmcnt drains.
__global__ __launch_bounds__(512, 2) void rnn_kernel(const float* __restrict__ Wh,
                                                     const f16* __restrict__ Z,
                                                     unsigned* mb0, unsigned* mb1,
                                                     float* __restrict__ h_final) {
  const int bid = blockIdx.x;
  const int g = bid >> 3, q = bid & 7;  // 16 groups x 8 j-blocks
  const int tid = threadIdx.x;
  const int l = tid & 63, w = tid >> 6;  // 8 waves
  const int lr = l & 15, lg = l >> 4;
  const int b0 = g * 16;
  const int jcol = q * 128 + w * 16 + lr;

  // mailbox-load geometry: per thread, 8 granules = (rows i*2+rb, dword cols 4u..4u+3)
  const int u = tid & 255;   // 8B-unit column index (0..255)
  const int rb = tid >> 8;   // row LSB

  // B-fragments of WhR row jcol (f32->f16 once): 128 VGPRs.
  half8 breg[32];
#pragma unroll
  for (int ks = 0; ks < 32; ++ks) {
    const float* s = &Wh[(size_t)jcol * 2048 + HIDDEN + ks * 32 + lg * 8];
    half8 hv;
#pragma unroll
    for (int i = 0; i < 8; ++i) hv[i] = (f16)s[i];
    breg[ks] = hv;
  }

  __shared__ f16 hs[16 * HIDDEN];  // 32KB, XOR-swizzled 16B granules

  // Zero the VMEM counter reality before hand-counted waits (compiler's own
  // counter model stays >= reality afterwards -> its waits remain safe no-ops).
  __builtin_amdgcn_sched_barrier(0);
  asm volatile("s_waitcnt vmcnt(0)" ::: "memory");

  unsigned zA[4], zB[4];
  // prologue: issue Z_0 loads (outstanding = 4 entering t=0)
  {
    const f16* zp = &Z[((size_t)0 * BATCH + b0 + lg * 4) * HIDDEN + jcol];
#pragma unroll
    for (int r = 0; r < 4; ++r)
      asm volatile("global_load_ushort %0, %1, off" : "=v"(zA[r]) : "v"(zp + r * HIDDEN));
  }

  auto step = [&](int t, unsigned (&zc)[4], unsigned (&zn)[4]) {
    const unsigned* mbr = (t & 1) ? mb1 : mb0;
    unsigned* mbw = (t & 1) ? mb0 : mb1;

    // 1) issue 8 mailbox dwordx4 loads (device-coherent)
    u32x4 hv[8];
#pragma unroll
    for (int i = 0; i < 8; ++i) {
      const unsigned* src = mbr + (size_t)(b0 + i * 2 + rb) * HIDDEN + u * 4;
      asm volatile("global_load_dwordx4 %0, %1, off sc0 sc1" : "=v"(hv[i]) : "v"(src));
    }
    // 2) issue Z(t+1) prefetch (plain cached)
    {
      int tp = (t + 1 < TSTEPS) ? t + 1 : TSTEPS - 1;
      const f16* zp = &Z[((size_t)tp * BATCH + b0 + lg * 4) * HIDDEN + jcol];
#pragma unroll
      for (int r = 0; r < 4; ++r)
        asm volatile("global_load_ushort %0, %1, off" : "=v"(zn[r]) : "v"(zp + r * HIDDEN));
    }
    // 3) wait: retires [Z_t, prev stores, h-loads]; Z(t+1) stays in flight
    asm volatile("s_waitcnt vmcnt(4)" ::: "memory");

    // 4) tag check + retry (common case: 0-2 retries)
    const unsigned texp = (unsigned)t << 16;
    int tries = 0;
    while (true) {
      unsigned bad = 0;
#pragma unroll
      for (int i = 0; i < 8; ++i) {
        bad |= hv[i][0] ^ texp;
        bad |= hv[i][1] ^ texp;
        bad |= hv[i][2] ^ texp;
        bad |= hv[i][3] ^ texp;
      }
      if (__ballot((bad >> 16) != 0u) == 0ull) break;
      if (++tries > (1 << 18)) break;  // fail-safe: wrong answer instead of hang
#pragma unroll
      for (int i = 0; i < 8; ++i) {
        const unsigned* src = mbr + (size_t)(b0 + i * 2 + rb) * HIDDEN + u * 4;
        asm volatile("global_load_dwordx4 %0, %1, off sc0 sc1" : "=v"(hv[i]) : "v"(src));
      }
      asm volatile("s_waitcnt vmcnt(0)" ::: "memory");
    }

    // 5) repack (strip tags) + stage into swizzled LDS
#pragma unroll
    for (int i = 0; i < 8; ++i) {
      asm volatile("" : "+v"(hv[i]));  // pin reads after the waitcnt asm
      unsigned p0 = (hv[i][0] & 0xffffu) | (hv[i][1] << 16);
      unsigned p1 = (hv[i][2] & 0xffffu) | (hv[i][3] << 16);
      int row = i * 2 + rb;
      int gI = u >> 1, half = u & 1;
      u32x2 pv = {p0, p1};
      *(u32x2*)((char*)hs + row * 2048 + ((gI ^ (row & 7)) * 16) + half * 8) = pv;
    }
    asm volatile("s_waitcnt lgkmcnt(0)" ::: "memory");
    __builtin_amdgcn_sched_barrier(0);
    __builtin_amdgcn_s_barrier();
    __builtin_amdgcn_sched_barrier(0);

    // 6) 4 independent accumulator chains of 8 dependent MFMAs
    f32x4 acc0 = {0.f, 0.f, 0.f, 0.f}, acc1 = acc0, acc2 = acc0, acc3 = acc0;
#pragma unroll
    for (int ks = 0; ks < 32; ks += 4) {
      int gA0 = ks * 4 + lg;
      half8 a0 = *(const half8*)&hs[lr * HIDDEN + ((gA0 ^ (lr & 7)) * 8)];
      half8 a1 = *(const half8*)&hs[lr * HIDDEN + (((gA0 + 4) ^ (lr & 7)) * 8)];
      half8 a2 = *(const half8*)&hs[lr * HIDDEN + (((gA0 + 8) ^ (lr & 7)) * 8)];
      half8 a3 = *(const half8*)&hs[lr * HIDDEN + (((gA0 + 12) ^ (lr & 7)) * 8)];
      acc0 = __builtin_amdgcn_mfma_f32_16x16x32_f16(a0, breg[ks + 0], acc0, 0, 0, 0);
      acc1 = __builtin_amdgcn_mfma_f32_16x16x32_f16(a1, breg[ks + 1], acc1, 0, 0, 0);
      acc2 = __builtin_amdgcn_mfma_f32_16x16x32_f16(a2, breg[ks + 2], acc2, 0, 0, 0);
      acc3 = __builtin_amdgcn_mfma_f32_16x16x32_f16(a3, breg[ks + 3], acc3, 0, 0, 0);
    }
    f32x4 acc = (acc0 + acc1) + (acc2 + acc3);

    // 7) add Z_t (in regs since last step), tanh, publish
#pragma unroll
    for (int r = 0; r < 4; ++r) asm volatile("" : "+v"(zc[r]));  // pin after vmcnt(4)
    float v0 = tanh_fast(acc[0] + (float)__builtin_bit_cast(f16, (unsigned short)zc[0]));
    float v1 = tanh_fast(acc[1] + (float)__builtin_bit_cast(f16, (unsigned short)zc[1]));
    float v2 = tanh_fast(acc[2] + (float)__builtin_bit_cast(f16, (unsigned short)zc[2]));
    float v3 = tanh_fast(acc[3] + (float)__builtin_bit_cast(f16, (unsigned short)zc[3]));

    if (t == TSTEPS - 1) {
      h_final[(size_t)(b0 + lg * 4 + 0) * HIDDEN + jcol] = v0;
      h_final[(size_t)(b0 + lg * 4 + 1) * HIDDEN + jcol] = v1;
      h_final[(size_t)(b0 + lg * 4 + 2) * HIDDEN + jcol] = v2;
      h_final[(size_t)(b0 + lg * 4 + 3) * HIDDEN + jcol] = v3;
    } else {
      const unsigned tag = (unsigned)(t + 1) << 16;
      unsigned d0 = (unsigned)__builtin_bit_cast(unsigned short, (f16)v0) | tag;
      unsigned d1 = (unsigned)__builtin_bit_cast(unsigned short, (f16)v1) | tag;
      unsigned d2 = (unsigned)__builtin_bit_cast(unsigned short, (f16)v2) | tag;
      unsigned d3 = (unsigned)__builtin_bit_cast(unsigned short, (f16)v3) | tag;
      unsigned* p0 = mbw + (size_t)(b0 + lg * 4) * HIDDEN + jcol;
      // fire-and-forget device-coherent stores (4 outstanding into next step)
      asm volatile("global_store_dword %0, %1, off sc0 sc1" ::"v"(p0), "v"(d0) : "memory");
      asm volatile("global_store_dword %0, %1, off sc0 sc1" ::"v"(p0 + HIDDEN), "v"(d1) : "memory");
      asm volatile("global_store_dword %0, %1, off sc0 sc1" ::"v"(p0 + 2 * HIDDEN), "v"(d2) : "memory");
      asm volatile("global_store_dword %0, %1, off sc0 sc1" ::"v"(p0 + 3 * HIDDEN), "v"(d3) : "memory");
    }
    // 8) LDS reuse guard: all waves done reading hs before next stage
    __builtin_amdgcn_sched_barrier(0);
    __builtin_amdgcn_s_barrier();
    __builtin_amdgcn_sched_barrier(0);
  };

  for (int t = 0; t < TSTEPS; t += 2) {
    step(t, zA, zB);
    step(t + 1, zB, zA);
  }
}

// ---------------- BatchNorm (training stats, biased var) + f16 cast ----------------
__global__ __launch_bounds__(256) void bn_kernel(const float* __restrict__ hf,
                                                 const float* __restrict__ gamma,
                                                 const float* __restrict__ beta,
                                                 f16* __restrict__ hbn) {
  int j = blockIdx.x * 256 + threadIdx.x;  // 1024 cols
  float s1 = 0.f, s2 = 0.f;
  for (int b = 0; b < BATCH; ++b) {
    float v = hf[(size_t)b * HIDDEN + j];
    s1 += v;
    s2 += v * v;
  }
  float mean = s1 * (1.f / BATCH);
  float var = s2 * (1.f / BATCH) - mean * mean;
  float sc = gamma[j] * rsqrtf(var + 1e-5f);
  float sh = beta[j] - mean * sc;
  for (int b = 0; b < BATCH; ++b)
    hbn[(size_t)b * HIDDEN + j] = (f16)(hf[(size_t)b * HIDDEN + j] * sc + sh);
}

// ---------------- launch ----------------
extern "C" void kernel_launch(void* const* d_in, const int* in_sizes, int n_in,
                              void* d_out, int out_size, void* d_ws, size_t ws_size,
                              hipStream_t stream) {
  (void)in_sizes; (void)n_in; (void)out_size;
  const float* x     = (const float*)d_in[0];
  const float* Wi    = (const float*)d_in[1];
  const float* bi    = (const float*)d_in[2];
  const float* Wh    = (const float*)d_in[3];
  const float* bh    = (const float*)d_in[4];
  const float* gamma = (const float*)d_in[5];
  const float* beta  = (const float*)d_in[6];
  const float* Wl    = (const float*)d_in[7];
  const float* bl    = (const float*)d_in[8];
  float* out = (float*)d_out;

  char* wsp = (char*)d_ws;
  size_t off = 0;
  auto alloc = [&](size_t bytes) -> void* {
    void* p = (void*)(wsp + off);
    off += (bytes + 255) & ~(size_t)255;
    return p;
  };
  f16*      Zb    = (f16*)alloc((size_t)TSTEPS * BATCH * HIDDEN * 2);  // 256 MB
  f16*      xT    = (f16*)alloc((size_t)TSTEPS * BATCH * NSER * 2);    // 128 MB
  f16*      WhLh  = (f16*)alloc((size_t)HIDDEN * HIDDEN * 2);
  f16*      WiT   = (f16*)alloc((size_t)NSER * HIDDEN * 2);
  f16*      Wlh   = (f16*)alloc((size_t)NSER * HIDDEN * 2);
  f16*      Weff  = (f16*)alloc((size_t)HIDDEN * NSER * 2);
  float*    beff  = (float*)alloc(HIDDEN * 4);
  unsigned* mb0   = (unsigned*)alloc((size_t)BATCH * HIDDEN * 4);  // 1 MB tagged mailbox
  unsigned* mb1   = (unsigned*)alloc((size_t)BATCH * HIDDEN * 4);  // 1 MB
  float*    hfin  = (float*)alloc((size_t)BATCH * HIDDEN * 4);
  f16*      hbn   = (f16*)alloc((size_t)BATCH * HIDDEN * 2);
  if (off > ws_size) return;  // workspace too small; fail visibly

  // mb0 = 0 -> tag 0 == h_0 (zeros); mb1 = 0 -> no stale tags from prior replay
  hipMemsetAsync(mb0, 0, (size_t)BATCH * HIDDEN * 4, stream);
  hipMemsetAsync(mb1, 0, (size_t)BATCH * HIDDEN * 4, stream);

  convert_whl_kernel<<<4096, 256, 0, stream>>>(Wh, WhLh);
  transpose_wi_kernel<<<dim3(16, 32), 256, 0, stream>>>(Wi, WiT);
  convert_wl_kernel<<<2048, 256, 0, stream>>>(Wl, Wlh);
  beff_kernel<<<1024, 256, 0, stream>>>(Wh, bi, bh, beff);
  // Weff[j][n] = sum_k WhL[j][k] * WiT[n][k] : M=1024, N=512, K=1024
  gemm_f16_kernel<true, false><<<dim3(4, 8), 256, 0, stream>>>(WhLh, WiT, nullptr, Weff,
                                                               1024, NSER, HIDDEN);
  transpose_x_kernel<<<dim3(16, 16, 256), 256, 0, stream>>>(x, xT);
  // Z[(t,b)][j] = sum_n xT[(t,b)][n] * Weff[j][n] + beff[j] : M=131072, N=1024, K=512
  gemm_f16_kernel<true, true><<<dim3(8, 1024), 256, 0, stream>>>(xT, Weff, beff, Zb,
                                                                 TSTEPS * BATCH, HIDDEN, NSER);
  rnn_kernel<<<128, 512, 0, stream>>>(Wh, Zb, mb0, mb1, hfin);
  bn_kernel<<<4, 256, 0, stream>>>(hfin, gamma, beta, hbn);
  // out[b][i] = sum_j hbn[b][j] * Wl[i][j] + bl[i] : M=256, N=512, K=1024
  gemm_f16_kernel<false, true><<<dim3(4, 2), 256, 0, stream>>>(hbn, Wlh, bl, out,
                                                               BATCH, NSER, HIDDEN);
}